// Round 1
// baseline (413.621 us; speedup 1.0000x reference)
//
#include <hip/hip_runtime.h>

// GCN: N=100k nodes, E=1.6M edges, H=64.
// Pipeline:
//   0. memset count=0
//   1. k_count:      in-degree histogram over dst (int atomics)
//   2. k_scan_local: per-1024-chunk exclusive scan of count -> rowstart, chunk totals
//   3. k_scan_blocks: scan the ~98 chunk totals
//   4. k_finalize:   rowstart += chunk offset; cursor=rowstart; dinv=rsqrt(deg+1)
//   5. k_fill:       CSR fill (csr_src grouped by dst)
//   6. k_node_transform: s[d] = dinv[d]*(sum dinv[s]x[s] + dinv[d]x[d]);
//                        g[d][j] = sum_k relu(s*w1[k]+b1[k]) * w2[k][j]   (w2 in LDS)
//   7. k_aggregate_out:  h2 = relu(dinv[d]*(sum dinv[s]g[s] + dinv[d]g[d]) + b2);
//                        out[d] = h2 . wfc + bfc   (wave=node, lane=channel)

#define HCH 64

__global__ __launch_bounds__(256) void k_count(const int* __restrict__ dst, int e,
                                               int* __restrict__ count) {
    int i = blockIdx.x * blockDim.x + threadIdx.x;
    if (i < e) atomicAdd(&count[dst[i]], 1);
}

// 1024 elements per block, 256 threads x 4
__global__ __launch_bounds__(256) void k_scan_local(const int* __restrict__ count, int n,
                                                    int* __restrict__ rowstart,
                                                    int* __restrict__ blocksums) {
    __shared__ int lds[256];
    int t = threadIdx.x;
    int base = blockIdx.x * 1024 + t * 4;
    int v[4];
    int s = 0;
#pragma unroll
    for (int k = 0; k < 4; k++) {
        int idx = base + k;
        v[k] = (idx < n) ? count[idx] : 0;
        s += v[k];
    }
    lds[t] = s;
    __syncthreads();
    for (int off = 1; off < 256; off <<= 1) {
        int add = (t >= off) ? lds[t - off] : 0;
        __syncthreads();
        lds[t] += add;
        __syncthreads();
    }
    int excl = lds[t] - s;
    if (t == 255) blocksums[blockIdx.x] = lds[255];
    int run = excl;
#pragma unroll
    for (int k = 0; k < 4; k++) {
        int idx = base + k;
        if (idx < n) rowstart[idx] = run;
        run += v[k];
    }
}

__global__ __launch_bounds__(128) void k_scan_blocks(int* __restrict__ blocksums, int nb) {
    __shared__ int lds[128];
    int t = threadIdx.x;
    int v = (t < nb) ? blocksums[t] : 0;
    lds[t] = v;
    __syncthreads();
    for (int off = 1; off < 128; off <<= 1) {
        int add = (t >= off) ? lds[t - off] : 0;
        __syncthreads();
        lds[t] += add;
        __syncthreads();
    }
    if (t < nb) blocksums[t] = lds[t] - v;  // exclusive
}

__global__ __launch_bounds__(256) void k_finalize(int* __restrict__ rowstart,
                                                  int* __restrict__ cursor,
                                                  float* __restrict__ dinv,
                                                  const int* __restrict__ count,
                                                  const int* __restrict__ blocksums, int n) {
    int i = blockIdx.x * blockDim.x + threadIdx.x;
    if (i < n) {
        int r = rowstart[i] + blocksums[i >> 10];
        rowstart[i] = r;
        cursor[i] = r;
        dinv[i] = rsqrtf((float)(count[i] + 1));  // +1 self loop; always > 0
    }
}

__global__ __launch_bounds__(256) void k_fill(const int* __restrict__ src,
                                              const int* __restrict__ dst, int e,
                                              int* __restrict__ cursor,
                                              int* __restrict__ csr_src) {
    int i = blockIdx.x * blockDim.x + threadIdx.x;
    if (i < e) {
        int d = dst[i];
        int pos = atomicAdd(&cursor[d], 1);
        csr_src[pos] = src[i];
    }
}

// one wave per node; lane = output channel of g
__global__ __launch_bounds__(256) void k_node_transform(
    const float* __restrict__ x, const int* __restrict__ csr_src,
    const int* __restrict__ rowstart, const int* __restrict__ count,
    const float* __restrict__ dinv, const float* __restrict__ w1,
    const float* __restrict__ b1, const float* __restrict__ w2,
    float* __restrict__ g, int n) {
    __shared__ float s_w2[HCH * HCH];
    __shared__ float s_w1[HCH];
    __shared__ float s_b1[HCH];
    int t = threadIdx.x;
    for (int i = t; i < HCH * HCH; i += 256) s_w2[i] = w2[i];
    if (t < HCH) { s_w1[t] = w1[t]; s_b1[t] = b1[t]; }
    __syncthreads();

    int wave = t >> 6, lane = t & 63;
    int node = blockIdx.x * 4 + wave;
    if (node >= n) return;

    int beg = rowstart[node], deg = count[node];
    float acc = 0.f;
    for (int ei = lane; ei < deg; ei += 64) {
        int sv = csr_src[beg + ei];
        acc += dinv[sv] * x[sv];
    }
#pragma unroll
    for (int off = 32; off; off >>= 1) acc += __shfl_xor(acc, off, 64);

    float dn = dinv[node];
    float sval = dn * (acc + dn * x[node]);

    float o = 0.f;
#pragma unroll 8
    for (int k = 0; k < HCH; k++) {
        float h = sval * s_w1[k] + s_b1[k];
        h = h > 0.f ? h : 0.f;
        o += h * s_w2[k * HCH + lane];
    }
    g[node * HCH + lane] = o;
}

// one wave per node; lane = channel; gather-reduce over in-edges, then FC dot
__global__ __launch_bounds__(256) void k_aggregate_out(
    const float* __restrict__ g, const int* __restrict__ csr_src,
    const int* __restrict__ rowstart, const int* __restrict__ count,
    const float* __restrict__ dinv, const float* __restrict__ b2,
    const float* __restrict__ wfc, const float* __restrict__ bfc,
    float* __restrict__ out, int n) {
    int t = threadIdx.x;
    int wave = t >> 6, lane = t & 63;
    int node = blockIdx.x * 4 + wave;
    if (node >= n) return;

    int beg = rowstart[node], deg = count[node];
    float acc = 0.f;
    int ei = 0;
    for (; ei + 3 < deg; ei += 4) {
        int s0 = csr_src[beg + ei + 0];
        int s1 = csr_src[beg + ei + 1];
        int s2 = csr_src[beg + ei + 2];
        int s3 = csr_src[beg + ei + 3];
        float w0 = dinv[s0], w1v = dinv[s1], w2v = dinv[s2], w3v = dinv[s3];
        float g0 = g[s0 * HCH + lane], g1 = g[s1 * HCH + lane];
        float g2 = g[s2 * HCH + lane], g3 = g[s3 * HCH + lane];
        acc += w0 * g0 + w1v * g1 + w2v * g2 + w3v * g3;
    }
    for (; ei < deg; ei++) {
        int s0 = csr_src[beg + ei];
        acc += dinv[s0] * g[s0 * HCH + lane];
    }
    float dn = dinv[node];
    acc += dn * g[node * HCH + lane];  // self loop
    float h = dn * acc + b2[lane];
    h = h > 0.f ? h : 0.f;
    float p = h * wfc[lane];
#pragma unroll
    for (int off = 32; off; off >>= 1) p += __shfl_xor(p, off, 64);
    if (lane == 0) out[node] = p + bfc[0];
}

extern "C" void kernel_launch(void* const* d_in, const int* in_sizes, int n_in,
                              void* d_out, int out_size, void* d_ws, size_t ws_size,
                              hipStream_t stream) {
    const float* x   = (const float*)d_in[0];
    const int*   ei  = (const int*)d_in[1];
    const float* w1  = (const float*)d_in[2];
    const float* b1  = (const float*)d_in[3];
    const float* w2  = (const float*)d_in[4];
    const float* b2  = (const float*)d_in[5];
    const float* wfc = (const float*)d_in[6];
    const float* bfc = (const float*)d_in[7];
    float* out = (float*)d_out;

    const int n = in_sizes[0];      // 100000
    const int e = in_sizes[1] / 2;  // 1600000
    const int* src = ei;
    const int* dst = ei + e;

    auto al = [](size_t v) { return (v + 255) & ~(size_t)255; };
    char* ws = (char*)d_ws;
    size_t o = 0;
    int* count    = (int*)(ws + o);  o = al(o + (size_t)n * 4);
    int* rowstart = (int*)(ws + o);  o = al(o + (size_t)n * 4);
    int* cursor   = (int*)(ws + o);  o = al(o + (size_t)n * 4);
    float* dinv   = (float*)(ws + o); o = al(o + (size_t)n * 4);
    int* blocksums = (int*)(ws + o);  o = al(o + (size_t)4096);
    int* csr_src  = (int*)(ws + o);  o = al(o + (size_t)e * 4);
    float* g      = (float*)(ws + o); o = al(o + (size_t)n * HCH * 4);
    (void)ws_size;

    const int nb = (n + 1023) / 1024;  // scan chunks (98 for n=100k)

    hipMemsetAsync(count, 0, (size_t)n * 4, stream);
    k_count<<<(e + 255) / 256, 256, 0, stream>>>(dst, e, count);
    k_scan_local<<<nb, 256, 0, stream>>>(count, n, rowstart, blocksums);
    k_scan_blocks<<<1, 128, 0, stream>>>(blocksums, nb);
    k_finalize<<<(n + 255) / 256, 256, 0, stream>>>(rowstart, cursor, dinv, count, blocksums, n);
    k_fill<<<(e + 255) / 256, 256, 0, stream>>>(src, dst, e, cursor, csr_src);

    int nblk = (n + 3) / 4;  // 4 waves (nodes) per 256-thread block
    k_node_transform<<<nblk, 256, 0, stream>>>(x, csr_src, rowstart, count, dinv,
                                               w1, b1, w2, g, n);
    k_aggregate_out<<<nblk, 256, 0, stream>>>(g, csr_src, rowstart, count, dinv,
                                              b2, wfc, bfc, out, n);
}

// Round 2
// 298.174 us; speedup vs baseline: 1.3872x; 1.3872x over previous
//
#include <hip/hip_runtime.h>

// GCN: N=100k nodes, E=1.6M edges, H=64.
// CSR build via two-level binning (fixes 16x write amplification of naive scatter):
//   1. k_hist:        per-chunk LDS histogram over dst>>9 -> global bucket_count (196 buckets)
//   2. k_scan_b:      exclusive scan of bucket_count -> bucket_base, init bucket_cursor
//   3. k_place:       per-chunk LDS histogram -> reserve per-bucket runs (1 atomic/bucket/block),
//                     write packed (localdst<<17 | src) as contiguous runs
//   4. k_bucket_sort: one WG per bucket; LDS counting sort over 512 local nodes ->
//                     csr_src grouped by node; emits rowstart, deg, dinv
// Compute:
//   5. k_node_transform: s[d] = dinv[d]*(sum dinv[s]x[s] + dinv[d]x[d]);
//                        g[d][:] = relu(s*w1+b1) @ w2   (w2 in LDS; wave=node, lane=channel)
//   6. k_aggregate_out:  h2 = relu(dinv[d]*(sum dinv[s]g[s] + dinv[d]g[d]) + b2);
//                        out[d] = h2 . wfc + bfc        (wave=node, lane=channel)

#define HCH 64
#define CHUNK 16384
#define BSH 9           // bucket shift: 512 nodes per bucket
#define BSZ 512

__global__ __launch_bounds__(256) void k_hist(const int* __restrict__ dst, int e,
                                              int* __restrict__ bucket_count) {
    __shared__ int h[256];
    int t = threadIdx.x;
    h[t] = 0;
    __syncthreads();
    int base = blockIdx.x * CHUNK;
    int end = min(e, base + CHUNK);
    for (int i = base + t; i < end; i += 256) atomicAdd(&h[dst[i] >> BSH], 1);
    __syncthreads();
    if (h[t]) atomicAdd(&bucket_count[t], h[t]);
}

__global__ __launch_bounds__(256) void k_scan_b(const int* __restrict__ bucket_count,
                                                int* __restrict__ bucket_base,
                                                int* __restrict__ bucket_cursor, int nb) {
    __shared__ int lds[256];
    int t = threadIdx.x;
    int v = (t < nb) ? bucket_count[t] : 0;
    lds[t] = v;
    __syncthreads();
    for (int off = 1; off < 256; off <<= 1) {
        int add = (t >= off) ? lds[t - off] : 0;
        __syncthreads();
        lds[t] += add;
        __syncthreads();
    }
    int base = lds[t] - v;  // exclusive
    bucket_base[t] = base;
    bucket_cursor[t] = base;
}

__global__ __launch_bounds__(256) void k_place(const int* __restrict__ src,
                                               const int* __restrict__ dst, int e,
                                               int* __restrict__ bucket_cursor,
                                               int* __restrict__ packed) {
    __shared__ int h[256];
    __shared__ int basel[256];
    int t = threadIdx.x;
    h[t] = 0;
    __syncthreads();
    int cbase = blockIdx.x * CHUNK;
    int cend = min(e, cbase + CHUNK);
    for (int i = cbase + t; i < cend; i += 256) atomicAdd(&h[dst[i] >> BSH], 1);
    __syncthreads();
    int my = h[t];
    __syncthreads();
    if (my) basel[t] = atomicAdd(&bucket_cursor[t], my);
    h[t] = 0;  // reuse as per-bucket local cursor
    __syncthreads();
    for (int i = cbase + t; i < cend; i += 256) {
        int d = dst[i];
        int b = d >> BSH;
        int loc = atomicAdd(&h[b], 1);
        packed[basel[b] + loc] = src[i] | ((d & (BSZ - 1)) << 17);
    }
}

__global__ __launch_bounds__(512) void k_bucket_sort(const int* __restrict__ packed,
                                                     const int* __restrict__ bucket_base,
                                                     const int* __restrict__ bucket_count,
                                                     int n,
                                                     int* __restrict__ csr_src,
                                                     int* __restrict__ rowstart,
                                                     int* __restrict__ deg,
                                                     float* __restrict__ dinv) {
    __shared__ int cnt[BSZ];
    int bk = blockIdx.x, t = threadIdx.x;
    int bbase = bucket_base[bk];
    int bcnt = bucket_count[bk];
    cnt[t] = 0;
    __syncthreads();
    for (int i = t; i < bcnt; i += BSZ) atomicAdd(&cnt[packed[bbase + i] >> 17], 1);
    __syncthreads();
    int my = cnt[t];
    // inclusive scan over cnt
    for (int off = 1; off < BSZ; off <<= 1) {
        int add = (t >= off) ? cnt[t - off] : 0;
        __syncthreads();
        cnt[t] += add;
        __syncthreads();
    }
    int excl = cnt[t] - my;
    int node = (bk << BSH) + t;
    if (node < n) {
        rowstart[node] = bbase + excl;
        deg[node] = my;
        dinv[node] = rsqrtf((float)(my + 1));  // +1 self-loop
    }
    cnt[t] = excl;  // reuse as per-node cursor
    __syncthreads();
    for (int i = t; i < bcnt; i += BSZ) {
        int p = packed[bbase + i];
        int pos = atomicAdd(&cnt[p >> 17], 1);
        csr_src[bbase + pos] = p & 0x1FFFF;
    }
}

// one wave per node; lane = output channel of g
__global__ __launch_bounds__(256) void k_node_transform(
    const float* __restrict__ x, const int* __restrict__ csr_src,
    const int* __restrict__ rowstart, const int* __restrict__ deg,
    const float* __restrict__ dinv, const float* __restrict__ w1,
    const float* __restrict__ b1, const float* __restrict__ w2,
    float* __restrict__ g, int n) {
    __shared__ float s_w2[HCH * HCH];
    __shared__ float s_w1[HCH];
    __shared__ float s_b1[HCH];
    int t = threadIdx.x;
    for (int i = t; i < HCH * HCH; i += 256) s_w2[i] = w2[i];
    if (t < HCH) { s_w1[t] = w1[t]; s_b1[t] = b1[t]; }
    __syncthreads();

    int wave = t >> 6, lane = t & 63;
    int node = blockIdx.x * 4 + wave;
    if (node >= n) return;

    int beg = rowstart[node], dg = deg[node];
    float acc = 0.f;
    for (int ei = lane; ei < dg; ei += 64) {
        int sv = csr_src[beg + ei];
        acc += dinv[sv] * x[sv];
    }
#pragma unroll
    for (int off = 32; off; off >>= 1) acc += __shfl_xor(acc, off, 64);

    float dn = dinv[node];
    float sval = dn * (acc + dn * x[node]);

    float o = 0.f;
#pragma unroll 8
    for (int k = 0; k < HCH; k++) {
        float h = sval * s_w1[k] + s_b1[k];
        h = h > 0.f ? h : 0.f;
        o += h * s_w2[k * HCH + lane];
    }
    g[node * HCH + lane] = o;
}

// one wave per node; lane = channel; gather-reduce over in-edges, then FC dot
__global__ __launch_bounds__(256) void k_aggregate_out(
    const float* __restrict__ g, const int* __restrict__ csr_src,
    const int* __restrict__ rowstart, const int* __restrict__ deg,
    const float* __restrict__ dinv, const float* __restrict__ b2,
    const float* __restrict__ wfc, const float* __restrict__ bfc,
    float* __restrict__ out, int n) {
    int t = threadIdx.x;
    int wave = t >> 6, lane = t & 63;
    int node = blockIdx.x * 4 + wave;
    if (node >= n) return;

    int beg = rowstart[node], dg = deg[node];
    float acc = 0.f;
    int ei = 0;
    for (; ei + 3 < dg; ei += 4) {
        int s0 = csr_src[beg + ei + 0];
        int s1 = csr_src[beg + ei + 1];
        int s2 = csr_src[beg + ei + 2];
        int s3 = csr_src[beg + ei + 3];
        float w0 = dinv[s0], w1v = dinv[s1], w2v = dinv[s2], w3v = dinv[s3];
        float g0 = g[s0 * HCH + lane], g1 = g[s1 * HCH + lane];
        float g2 = g[s2 * HCH + lane], g3 = g[s3 * HCH + lane];
        acc += w0 * g0 + w1v * g1 + w2v * g2 + w3v * g3;
    }
    for (; ei < dg; ei++) {
        int s0 = csr_src[beg + ei];
        acc += dinv[s0] * g[s0 * HCH + lane];
    }
    float dn = dinv[node];
    acc += dn * g[node * HCH + lane];  // self loop
    float h = dn * acc + b2[lane];
    h = h > 0.f ? h : 0.f;
    float p = h * wfc[lane];
#pragma unroll
    for (int off = 32; off; off >>= 1) p += __shfl_xor(p, off, 64);
    if (lane == 0) out[node] = p + bfc[0];
}

extern "C" void kernel_launch(void* const* d_in, const int* in_sizes, int n_in,
                              void* d_out, int out_size, void* d_ws, size_t ws_size,
                              hipStream_t stream) {
    const float* x   = (const float*)d_in[0];
    const int*   ei  = (const int*)d_in[1];
    const float* w1  = (const float*)d_in[2];
    const float* b1  = (const float*)d_in[3];
    const float* w2  = (const float*)d_in[4];
    const float* b2  = (const float*)d_in[5];
    const float* wfc = (const float*)d_in[6];
    const float* bfc = (const float*)d_in[7];
    float* out = (float*)d_out;

    const int n = in_sizes[0];      // 100000
    const int e = in_sizes[1] / 2;  // 1600000
    const int* src = ei;
    const int* dst = ei + e;

    auto al = [](size_t v) { return (v + 255) & ~(size_t)255; };
    char* ws = (char*)d_ws;
    size_t o = 0;
    int* bucket_count  = (int*)(ws + o); o = al(o + 256 * 4);
    int* bucket_base   = (int*)(ws + o); o = al(o + 256 * 4);
    int* bucket_cursor = (int*)(ws + o); o = al(o + 256 * 4);
    int* rowstart = (int*)(ws + o);   o = al(o + (size_t)n * 4);
    int* deg      = (int*)(ws + o);   o = al(o + (size_t)n * 4);
    float* dinv   = (float*)(ws + o); o = al(o + (size_t)n * 4);
    int* csr_src  = (int*)(ws + o);   o = al(o + (size_t)e * 4);
    // packed and g alias: packed consumed by k_bucket_sort before g is written
    int* packed   = (int*)(ws + o);
    float* g      = (float*)(ws + o);
    (void)ws_size;

    const int nb = (n + BSZ - 1) >> BSH;            // 196 buckets
    const int nchunk = (e + CHUNK - 1) / CHUNK;     // 98 chunks

    hipMemsetAsync(bucket_count, 0, 256 * 4, stream);
    k_hist<<<nchunk, 256, 0, stream>>>(dst, e, bucket_count);
    k_scan_b<<<1, 256, 0, stream>>>(bucket_count, bucket_base, bucket_cursor, nb);
    k_place<<<nchunk, 256, 0, stream>>>(src, dst, e, bucket_cursor, packed);
    k_bucket_sort<<<nb, BSZ, 0, stream>>>(packed, bucket_base, bucket_count, n,
                                          csr_src, rowstart, deg, dinv);

    int nblk = (n + 3) / 4;  // 4 waves (nodes) per 256-thread block
    k_node_transform<<<nblk, 256, 0, stream>>>(x, csr_src, rowstart, deg, dinv,
                                               w1, b1, w2, g, n);
    k_aggregate_out<<<nblk, 256, 0, stream>>>(g, csr_src, rowstart, deg, dinv,
                                              b2, wfc, bfc, out, n);
}